// Round 15
// baseline (642.917 us; speedup 1.0000x reference)
//
#include <hip/hip_runtime.h>
#include <cstdint>
#include <cstddef>

// Problem shape (fixed by setup_inputs)
#define NND   10000     // nodes per graph
#define NED   160000    // edges per graph
#define NB    8         // batch
#define NF    256       // in features
#define NHID  64        // hidden per head
#define HEADS 8
#define F1    512       // HEADS*NHID
#define NCLS  64        // out classes

#define QSH   10        // dst-block shift (1024 nodes = 1MB h1 window)
#define NQ    10        // ceil(NND / 1024)
#define NK    (NND * NQ)  // composite key space per batch

#define ALPHA_SLOPE 0.2f
#define OUT_SLOPE   0.01f
#define EPS         1e-16f

typedef unsigned short u16;
typedef short short8 __attribute__((ext_vector_type(8)));
typedef float f32x4 __attribute__((ext_vector_type(4)));

// ---------------- ws layout (byte offsets, 16B-aligned) ----------------
static const size_t B_WCHI = 0;                      // u16 frag-order gemm1 B
static const size_t B_WCLO = 262144;
static const size_t B_WOHI = 524288;                 // u16 frag-order gemm2 B
static const size_t B_WOLO = 589824;
static const size_t B_AS1  = 655360;                 // f32 [8][N][8]
static const size_t B_AD1  = 3215360;
static const size_t B_AS2  = 5775360;                // f32 [8][N]
static const size_t B_AD2  = 6095360;
static const size_t B_CNT  = 6415360;                // int [8][NK]  (3.2MB)
static const size_t B_CUR  = 9615360;                // int [8][NK]  (3.2MB)
static const size_t B_ROWS = 12815360;               // int [8][N+1]
static const size_t B_DST  = 13135424;               // u16 [8][E]
static const size_t B_SCR  = 15695424;               // Z slots
// per-z slot layout in u16 units (ZSTRU total):
//   off 0:          xchi [N][F1]
//   off 5,120,000:  xclo [N][F1]
//   off 10,240,000: h1   [N][F1]   (node-major)
//   off 15,360,000: h2   [N][NCLS]
#define ZSTRU 16000000ull
static const size_t S_PERZ = 2 * ZSTRU;              // bytes = 32,000,000

// ---------------- helpers ----------------
__device__ __forceinline__ u16 f32_to_bf16_rn(float f) {
  uint32_t u = __float_as_uint(f);
  uint32_t r = u + 0x7fffu + ((u >> 16) & 1u);
  return (u16)(r >> 16);
}
__device__ __forceinline__ float bf16_to_f32(u16 s) {
  return __uint_as_float((uint32_t)s << 16);
}
__device__ __forceinline__ void split1(float v, u16& h, u16& l) {
  h = f32_to_bf16_rn(v);
  float r = v - bf16_to_f32(h);
  l = f32_to_bf16_rn(r);
}

// ---------------- weight prep ----------------
// W_heads -> MFMA-fragment-order: frag = ((by*8 + ts)*4 + wq)*4 + nj; per frag
// 64 lanes x 8 u16. Element (lane,j): n = by*256+wq*64+nj*16+(lane&15),
// k = ts*32 + (lane>>4)*8 + j. One wave's fragment load = 1KB contiguous.
__global__ __launch_bounds__(256) void k_wsplit1(const float* __restrict__ Whd,
                                                 u16* __restrict__ hi,
                                                 u16* __restrict__ lo) {
  int t = blockIdx.x * 256 + threadIdx.x;   // 16384 threads
  int lane = t & 63;
  int frag = t >> 6;                        // 0..255
  int nj = frag & 3;
  int wq = (frag >> 2) & 3;
  int ts = (frag >> 4) & 7;
  int by = frag >> 7;
  int lm = lane & 15, lkg = lane >> 4;
  int n = by * 256 + wq * 64 + nj * 16 + lm;
  int h = n >> 6, nc = n & 63;
  u16 hv[8], lv[8];
#pragma unroll
  for (int j = 0; j < 8; ++j) {
    int k = ts * 32 + lkg * 8 + j;
    split1(Whd[h * (NF * NHID) + k * NHID + nc], hv[j], lv[j]);
  }
  size_t o = (size_t)t * 8;
  *(ushort4*)(hi + o) = make_ushort4(hv[0], hv[1], hv[2], hv[3]);
  *(ushort4*)(hi + o + 4) = make_ushort4(hv[4], hv[5], hv[6], hv[7]);
  *(ushort4*)(lo + o) = make_ushort4(lv[0], lv[1], lv[2], lv[3]);
  *(ushort4*)(lo + o + 4) = make_ushort4(lv[4], lv[5], lv[6], lv[7]);
}

// W_out -> frag order: frag = ts*4 + nj (ts 0..15); element (lane,j):
// n = nj*16 + (lane&15), k = ts*32 + (lane>>4)*8 + j.
__global__ __launch_bounds__(256) void k_wsplit2(const float* __restrict__ Wo,
                                                 u16* __restrict__ hi,
                                                 u16* __restrict__ lo) {
  int t = blockIdx.x * 256 + threadIdx.x;   // 4096 threads
  int lane = t & 63;
  int frag = t >> 6;                        // 0..63
  int nj = frag & 3, ts = frag >> 2;
  int lm = lane & 15, lkg = lane >> 4;
  int n = nj * 16 + lm;
  u16 hv[8], lv[8];
#pragma unroll
  for (int j = 0; j < 8; ++j) {
    int k = ts * 32 + lkg * 8 + j;
    split1(Wo[k * NCLS + n], hv[j], lv[j]);
  }
  size_t o = (size_t)t * 8;
  *(ushort4*)(hi + o) = make_ushort4(hv[0], hv[1], hv[2], hv[3]);
  *(ushort4*)(hi + o + 4) = make_ushort4(hv[4], hv[5], hv[6], hv[7]);
  *(ushort4*)(lo + o) = make_ushort4(lv[0], lv[1], lv[2], lv[3]);
  *(ushort4*)(lo + o + 4) = make_ushort4(lv[4], lv[5], lv[6], lv[7]);
}

// ---------------- layer-1 GEMM: BM=64, BN=512; 512 thr, 8 waves = 8 heads ---
__global__ __launch_bounds__(512) void k_gemm1(
    const float* __restrict__ x,
    const u16* __restrict__ Bfh, const u16* __restrict__ Bfl,
    u16* __restrict__ h1_s,
    const float* __restrict__ avec,
    float* __restrict__ as_g, float* __restrict__ ad_g,
    int base_b, int zsh) {
  __shared__ u16 As_hi[64][40];
  __shared__ u16 As_lo[64][40];

  const int zmask = (1 << zsh) - 1;
  const int z = blockIdx.x & zmask;
  const int wg = blockIdx.x >> zsh;        // 0..156
  const int b = base_b + z;
  const float* A = x + (size_t)b * NND * NF;
  u16* C = h1_s + (size_t)z * ZSTRU;
  float* as_ = as_g + (size_t)b * NND * 8;
  float* ad_ = ad_g + (size_t)b * NND * 8;

  const int m0 = wg * 64;
  const int tid = threadIdx.x;
  const int lane = tid & 63;
  const int w = tid >> 6;            // 0..7 == head
  const int lm = lane & 15;
  const int lkg = lane >> 4;
  const int by = w >> 2, wq = w & 3;

  f32x4 acc[4][4];
#pragma unroll
  for (int mi = 0; mi < 4; ++mi)
#pragma unroll
    for (int nj = 0; nj < 4; ++nj) acc[mi][nj] = 0.f;

  for (int t = 0; t < 8; ++t) {
    const int kk = t * 32;
    __syncthreads();
    {
      int rr = tid >> 3, kf = (tid & 7) * 4;
      int gm = m0 + rr;
      float4 v = make_float4(0.f, 0.f, 0.f, 0.f);
      if (gm < NND) v = *(const float4*)(A + (size_t)gm * NF + kk + kf);
      ushort4 hv, lv;
      split1(v.x, hv.x, lv.x); split1(v.y, hv.y, lv.y);
      split1(v.z, hv.z, lv.z); split1(v.w, hv.w, lv.w);
      *(ushort4*)&As_hi[rr][kf] = hv;
      *(ushort4*)&As_lo[rr][kf] = lv;
    }
    short8 bh[4], bl[4];
    {
      size_t fb = (((size_t)(by * 8 + t) * 4 + wq) * 4) * 512 + (size_t)lane * 8;
#pragma unroll
      for (int nj = 0; nj < 4; ++nj) {
        bh[nj] = *(const short8*)(Bfh + fb + nj * 512);
        bl[nj] = *(const short8*)(Bfl + fb + nj * 512);
      }
    }
    __syncthreads();

    short8 ah[4], al[4];
#pragma unroll
    for (int mi = 0; mi < 4; ++mi) {
      int row = mi * 16 + lm;
      ah[mi] = *(const short8*)&As_hi[row][lkg * 8];
      al[mi] = *(const short8*)&As_lo[row][lkg * 8];
    }
#pragma unroll
    for (int mi = 0; mi < 4; ++mi)
#pragma unroll
      for (int nj = 0; nj < 4; ++nj) {
        acc[mi][nj] = __builtin_amdgcn_mfma_f32_16x16x32_bf16(ah[mi], bh[nj], acc[mi][nj], 0, 0, 0);
        acc[mi][nj] = __builtin_amdgcn_mfma_f32_16x16x32_bf16(ah[mi], bl[nj], acc[mi][nj], 0, 0, 0);
        acc[mi][nj] = __builtin_amdgcn_mfma_f32_16x16x32_bf16(al[mi], bh[nj], acc[mi][nj], 0, 0, 0);
      }
  }

  const int hb = w;
  const int n0 = w * 64;
  float a_sv[4], a_dv[4];
#pragma unroll
  for (int nj = 0; nj < 4; ++nj) {
    a_sv[nj] = avec[hb * 128 + nj * 16 + lm];
    a_dv[nj] = avec[hb * 128 + 64 + nj * 16 + lm];
  }
#pragma unroll
  for (int mi = 0; mi < 4; ++mi) {
#pragma unroll
    for (int rr = 0; rr < 4; ++rr) {
      int gm = m0 + mi * 16 + lkg * 4 + rr;
      float ps = acc[mi][0][rr] * a_sv[0] + acc[mi][1][rr] * a_sv[1] +
                 acc[mi][2][rr] * a_sv[2] + acc[mi][3][rr] * a_sv[3];
      float pd = acc[mi][0][rr] * a_dv[0] + acc[mi][1][rr] * a_dv[1] +
                 acc[mi][2][rr] * a_dv[2] + acc[mi][3][rr] * a_dv[3];
#pragma unroll
      for (int off = 1; off < 16; off <<= 1) {
        ps += __shfl_xor(ps, off, 16);
        pd += __shfl_xor(pd, off, 16);
      }
      if (gm < NND) {
#pragma unroll
        for (int nj = 0; nj < 4; ++nj)
          C[(size_t)gm * F1 + n0 + nj * 16 + lm] = f32_to_bf16_rn(acc[mi][nj][rr]);
        if (lm == 0) {
          as_[(size_t)gm * 8 + hb] = ps;
          ad_[(size_t)gm * 8 + hb] = pd;
        }
      }
    }
  }
}

// ---------------- layer-2 GEMM: BM=64 (4 waves x 16 rows), BN=64 ------------
__global__ __launch_bounds__(256) void k_gemm2(
    const u16* __restrict__ Ahi_s, const u16* __restrict__ Alo_s,
    const u16* __restrict__ Bfh, const u16* __restrict__ Bfl,
    u16* __restrict__ C_s,
    const float* __restrict__ avec,
    float* __restrict__ as_g, float* __restrict__ ad_g,
    int base_b, int zsh) {
  __shared__ u16 As_hi[64][40];
  __shared__ u16 As_lo[64][40];

  const int zmask = (1 << zsh) - 1;
  const int z = blockIdx.x & zmask;
  const int wg = blockIdx.x >> zsh;        // 0..156
  const int b = base_b + z;
  const u16* Ahi = Ahi_s + (size_t)z * ZSTRU;
  const u16* Alo = Alo_s + (size_t)z * ZSTRU;
  u16* C = C_s + (size_t)z * ZSTRU;
  float* as_ = as_g + (size_t)b * NND;
  float* ad_ = ad_g + (size_t)b * NND;

  const int tid = threadIdx.x;
  const int lane = tid & 63;
  const int w = tid >> 6;
  const int lm = lane & 15;
  const int lkg = lane >> 4;
  const int m0 = wg * 64;

  f32x4 acc[4];
#pragma unroll
  for (int j = 0; j < 4; ++j) acc[j] = 0.f;

  for (int ts = 0; ts < 16; ++ts) {
    const int kk = ts * 32;
    __syncthreads();
#pragma unroll
    for (int u = 0; u < 2; ++u) {
      int e = u * 256 + tid;
      int rr = e >> 3, kf = (e & 7) * 4;
      int gm = m0 + rr;
      ushort4 hv = make_ushort4(0, 0, 0, 0), lv = make_ushort4(0, 0, 0, 0);
      if (gm < NND) {
        size_t g = (size_t)gm * F1 + kk + kf;
        hv = *(const ushort4*)(Ahi + g);
        lv = *(const ushort4*)(Alo + g);
      }
      *(ushort4*)&As_hi[rr][kf] = hv;
      *(ushort4*)&As_lo[rr][kf] = lv;
    }
    short8 bh[4], bl[4];
    {
      size_t fb = (size_t)(ts * 4) * 512 + (size_t)lane * 8;
#pragma unroll
      for (int nj = 0; nj < 4; ++nj) {
        bh[nj] = *(const short8*)(Bfh + fb + nj * 512);
        bl[nj] = *(const short8*)(Bfl + fb + nj * 512);
      }
    }
    __syncthreads();

    short8 ah, al;
    {
      int row = w * 16 + lm;
      ah = *(const short8*)&As_hi[row][lkg * 8];
      al = *(const short8*)&As_lo[row][lkg * 8];
    }
#pragma unroll
    for (int nj = 0; nj < 4; ++nj) {
      acc[nj] = __builtin_amdgcn_mfma_f32_16x16x32_bf16(ah, bh[nj], acc[nj], 0, 0, 0);
      acc[nj] = __builtin_amdgcn_mfma_f32_16x16x32_bf16(ah, bl[nj], acc[nj], 0, 0, 0);
      acc[nj] = __builtin_amdgcn_mfma_f32_16x16x32_bf16(al, bh[nj], acc[nj], 0, 0, 0);
    }
  }

  float a_sv[4], a_dv[4];
#pragma unroll
  for (int nj = 0; nj < 4; ++nj) {
    a_sv[nj] = avec[nj * 16 + lm];
    a_dv[nj] = avec[64 + nj * 16 + lm];
  }
#pragma unroll
  for (int rr = 0; rr < 4; ++rr) {
    int gm = m0 + w * 16 + lkg * 4 + rr;
    float ps = acc[0][rr] * a_sv[0] + acc[1][rr] * a_sv[1] +
               acc[2][rr] * a_sv[2] + acc[3][rr] * a_sv[3];
    float pd = acc[0][rr] * a_dv[0] + acc[1][rr] * a_dv[1] +
               acc[2][rr] * a_dv[2] + acc[3][rr] * a_dv[3];
#pragma unroll
    for (int off = 1; off < 16; off <<= 1) {
      ps += __shfl_xor(ps, off, 16);
      pd += __shfl_xor(pd, off, 16);
    }
    if (gm < NND) {
#pragma unroll
      for (int nj = 0; nj < 4; ++nj)
        C[(size_t)gm * NCLS + nj * 16 + lm] = f32_to_bf16_rn(acc[nj][rr]);
      if (lm == 0) {
        as_[gm] = ps;
        ad_[gm] = pd;
      }
    }
  }
}

// ---- counting sort on composite key (src, dst>>QSH) — all XCD-pinned ----
// Segments come out sorted by dst-block: concurrent waves sweep dst-windows
// together -> h1 gathers cluster in ~1-2MB L2-resident windows.

__global__ __launch_bounds__(256) void k_hist(const int* __restrict__ ei,
                                              int* __restrict__ counts) {
  int z = blockIdx.x & 7;
  int blk = blockIdx.x >> 3;
  int e = blk * 256 + threadIdx.x;
  if (e < NED) {
    int s = ei[(size_t)z * 2 * NED + e];
    int d = ei[(size_t)z * 2 * NED + NED + e];
    atomicAdd(&counts[(size_t)z * NK + s * NQ + (d >> QSH)], 1);
  }
}

// streaming two-pass scan over NK keys; one block (1024 thr) per batch.
__global__ __launch_bounds__(1024) void k_scan(const int* __restrict__ counts,
                                               int* __restrict__ rows,
                                               int* __restrict__ cursor) {
  __shared__ int lds[1024];
  const int b = blockIdx.x;
  const int tid = threadIdx.x;
  const int* cb = counts + (size_t)b * NK;
  int* cu = cursor + (size_t)b * NK;
  int* rb = rows + b * (NND + 1);
  const int per = (NK + 1023) / 1024;   // 98
  const int base = tid * per;
  int s = 0;
  for (int j = 0; j < per; ++j) {
    int i = base + j;
    if (i < NK) s += cb[i];
  }
  lds[tid] = s;
  __syncthreads();
  for (int off = 1; off < 1024; off <<= 1) {
    int t = (tid >= off) ? lds[tid - off] : 0;
    __syncthreads();
    lds[tid] += t;
    __syncthreads();
  }
  int run = lds[tid] - s;   // exclusive prefix of this thread's chunk
  for (int j = 0; j < per; ++j) {
    int i = base + j;
    if (i < NK) { cu[i] = run; run += cb[i]; }
  }
  __syncthreads();
  for (int n = tid; n < NND; n += 1024) rb[n] = cu[n * NQ];
  if (tid == 0) rb[NND] = NED;
}

__global__ __launch_bounds__(256) void k_scatter(const int* __restrict__ ei,
                                                 int* __restrict__ cursor,
                                                 u16* __restrict__ dst_s) {
  int z = blockIdx.x & 7;
  int blk = blockIdx.x >> 3;
  int e = blk * 256 + threadIdx.x;
  if (e < NED) {
    int s = ei[(size_t)z * 2 * NED + e];
    int d = ei[(size_t)z * 2 * NED + NED + e];
    int pos = atomicAdd(&cursor[(size_t)z * NK + s * NQ + (d >> QSH)], 1);
    dst_s[(size_t)z * NED + pos] = (u16)d;
  }
}

#define UPK8(q, e) do { \
  acc[0] = fmaf(e, __uint_as_float((q).x << 16), acc[0]); \
  acc[1] = fmaf(e, __uint_as_float((q).x & 0xffff0000u), acc[1]); \
  acc[2] = fmaf(e, __uint_as_float((q).y << 16), acc[2]); \
  acc[3] = fmaf(e, __uint_as_float((q).y & 0xffff0000u), acc[3]); \
  acc[4] = fmaf(e, __uint_as_float((q).z << 16), acc[4]); \
  acc[5] = fmaf(e, __uint_as_float((q).z & 0xffff0000u), acc[5]); \
  acc[6] = fmaf(e, __uint_as_float((q).w << 16), acc[6]); \
  acc[7] = fmaf(e, __uint_as_float((q).w & 0xffff0000u), acc[7]); \
} while (0)

#define LKY(t) ((t) >= 0.f ? (t) : ALPHA_SLOPE * (t))

// layer-1 CSR agg, fused score + elu, writes split-bf16 xc. one wave/node.
// lane l owns features l*8..l*8+7 (16B of the bf16 h1 row), head = l>>3.
__global__ __launch_bounds__(256) void k_agg1(
    const int* __restrict__ rows_g, const u16* __restrict__ dst_g,
    const u16* __restrict__ h1_s,
    const float* __restrict__ as_g, const float* __restrict__ ad_g,
    u16* __restrict__ xchi_s, u16* __restrict__ xclo_s,
    int base_b, int zsh) {
  const int zmask = (1 << zsh) - 1;
  const int z = blockIdx.x & zmask;
  const int idx = blockIdx.x >> zsh;       // 0..2499
  const int b = base_b + z;
  const int* rows = rows_g + (size_t)b * (NND + 1);
  const u16* dst = dst_g + (size_t)b * NED;
  const u16* h1 = h1_s + (size_t)z * ZSTRU;
  const float* as_ = as_g + (size_t)b * NND * 8;
  const float* ad_ = ad_g + (size_t)b * NND * 8;
  u16* xh = xchi_s + (size_t)z * ZSTRU;
  u16* xl = xclo_s + (size_t)z * ZSTRU;

  int lane = threadIdx.x & 63;
  int n = (idx * 256 + threadIdx.x) >> 6;
  if (n >= NND) return;
  const int hh = lane >> 3;
  const float asv = as_[n * 8 + hh];
  int beg = rows[n], end = rows[n + 1];
  float acc[8] = {};
  float den = 0.f;
  int i = beg;
  for (; i + 4 <= end; i += 4) {
    int d0 = dst[i], d1 = dst[i + 1], d2 = dst[i + 2], d3 = dst[i + 3];
    float t0 = LKY(asv + ad_[d0 * 8 + hh]);
    float t1 = LKY(asv + ad_[d1 * 8 + hh]);
    float t2 = LKY(asv + ad_[d2 * 8 + hh]);
    float t3 = LKY(asv + ad_[d3 * 8 + hh]);
    float e0 = __expf(-t0), e1 = __expf(-t1);
    float e2 = __expf(-t2), e3 = __expf(-t3);
    uint4 q0 = *((const uint4*)(h1 + (size_t)d0 * F1) + lane);
    uint4 q1 = *((const uint4*)(h1 + (size_t)d1 * F1) + lane);
    uint4 q2 = *((const uint4*)(h1 + (size_t)d2 * F1) + lane);
    uint4 q3 = *((const uint4*)(h1 + (size_t)d3 * F1) + lane);
    UPK8(q0, e0); UPK8(q1, e1); UPK8(q2, e2); UPK8(q3, e3);
    den += (e0 + e1) + (e2 + e3);
  }
  for (; i < end; ++i) {
    int d0 = dst[i];
    float t0 = LKY(asv + ad_[d0 * 8 + hh]);
    float e0 = __expf(-t0);
    uint4 q0 = *((const uint4*)(h1 + (size_t)d0 * F1) + lane);
    UPK8(q0, e0);
    den += e0;
  }
  float inv = 1.f / (den + EPS);
  u16 oh[8], ol[8];
#pragma unroll
  for (int j = 0; j < 8; ++j) {
    float v = acc[j] * inv;
    v = v > 0.f ? v : expm1f(v);
    split1(v, oh[j], ol[j]);
  }
  size_t wo = (size_t)n * F1 + lane * 8;
  *(ushort4*)(xh + wo) = make_ushort4(oh[0], oh[1], oh[2], oh[3]);
  *(ushort4*)(xh + wo + 4) = make_ushort4(oh[4], oh[5], oh[6], oh[7]);
  *(ushort4*)(xl + wo) = make_ushort4(ol[0], ol[1], ol[2], ol[3]);
  *(ushort4*)(xl + wo + 4) = make_ushort4(ol[4], ol[5], ol[6], ol[7]);
}

// layer-2 CSR agg, fused score + leaky output. one wave/node, lane=feature.
__global__ __launch_bounds__(256) void k_agg2(
    const int* __restrict__ rows_g, const u16* __restrict__ dst_g,
    const u16* __restrict__ h2_s,
    const float* __restrict__ as_g, const float* __restrict__ ad_g,
    float* __restrict__ out, int base_b, int zsh) {
  const int zmask = (1 << zsh) - 1;
  const int z = blockIdx.x & zmask;
  const int idx = blockIdx.x >> zsh;
  const int b = base_b + z;
  const int* rows = rows_g + (size_t)b * (NND + 1);
  const u16* dst = dst_g + (size_t)b * NED;
  const u16* h2 = h2_s + (size_t)z * ZSTRU;
  const float* as_ = as_g + (size_t)b * NND;
  const float* ad_ = ad_g + (size_t)b * NND;
  float* ob = out + (size_t)b * NND * NCLS;

  int lane = threadIdx.x & 63;
  int n = (idx * 256 + threadIdx.x) >> 6;
  if (n >= NND) return;
  const float asv = as_[n];
  int beg = rows[n], end = rows[n + 1];
  float acc = 0.f, den = 0.f;
  int i = beg;
  for (; i + 4 <= end; i += 4) {
    int d0 = dst[i], d1 = dst[i + 1], d2 = dst[i + 2], d3 = dst[i + 3];
    float t0 = LKY(asv + ad_[d0]);
    float t1 = LKY(asv + ad_[d1]);
    float t2 = LKY(asv + ad_[d2]);
    float t3 = LKY(asv + ad_[d3]);
    float e0 = __expf(-t0), e1 = __expf(-t1);
    float e2 = __expf(-t2), e3 = __expf(-t3);
    float h0 = bf16_to_f32(h2[(size_t)d0 * NCLS + lane]);
    float h1v = bf16_to_f32(h2[(size_t)d1 * NCLS + lane]);
    float h2v = bf16_to_f32(h2[(size_t)d2 * NCLS + lane]);
    float h3v = bf16_to_f32(h2[(size_t)d3 * NCLS + lane]);
    acc = fmaf(e0, h0, acc); acc = fmaf(e1, h1v, acc);
    acc = fmaf(e2, h2v, acc); acc = fmaf(e3, h3v, acc);
    den += (e0 + e1) + (e2 + e3);
  }
  for (; i < end; ++i) {
    int d0 = dst[i];
    float t0 = LKY(asv + ad_[d0]);
    float e0 = __expf(-t0);
    acc = fmaf(e0, bf16_to_f32(h2[(size_t)d0 * NCLS + lane]), acc);
    den += e0;
  }
  float v = acc / (den + EPS);
  ob[(size_t)n * NCLS + lane] = v >= 0.f ? v : OUT_SLOPE * v;
}

// ---------------- launcher ----------------
extern "C" void kernel_launch(void* const* d_in, const int* in_sizes, int n_in,
                              void* d_out, int out_size, void* d_ws, size_t ws_size,
                              hipStream_t stream) {
  const float* x       = (const float*)d_in[0];   // [B,N,256]
  const int*   ei      = (const int*)d_in[1];     // [B,2,E]
  const float* W_heads = (const float*)d_in[2];   // [8,256,64]
  const float* a_heads = (const float*)d_in[3];   // [8,128]
  const float* W_out   = (const float*)d_in[4];   // [512,64]
  const float* a_out   = (const float*)d_in[5];   // [128]
  float* out = (float*)d_out;

  char* base = (char*)d_ws;
  u16* wchi = (u16*)(base + B_WCHI);
  u16* wclo = (u16*)(base + B_WCLO);
  u16* wohi = (u16*)(base + B_WOHI);
  u16* wolo = (u16*)(base + B_WOLO);
  float* as1 = (float*)(base + B_AS1);
  float* ad1 = (float*)(base + B_AD1);
  float* as2 = (float*)(base + B_AS2);
  float* ad2 = (float*)(base + B_AD2);
  int* counts    = (int*)(base + B_CNT);
  int* cursor    = (int*)(base + B_CUR);
  int* rows      = (int*)(base + B_ROWS);
  u16* dst_s     = (u16*)(base + B_DST);
  u16* scr       = (u16*)(base + B_SCR);

  int Z = 1, zsh = 0;
  if (ws_size >= B_SCR + 8 * S_PERZ) { Z = 8; zsh = 3; }
  else if (ws_size >= B_SCR + 4 * S_PERZ) { Z = 4; zsh = 2; }
  else if (ws_size >= B_SCR + 2 * S_PERZ) { Z = 2; zsh = 1; }

  u16* xchi = scr + 0;
  u16* xclo = scr + 5120000;
  u16* h1   = scr + 10240000;
  u16* h2   = scr + 15360000;

  // weight prep (once per call)
  k_wsplit1<<<64, 256, 0, stream>>>(W_heads, wchi, wclo);
  k_wsplit2<<<16, 256, 0, stream>>>(W_out, wohi, wolo);

  // ---- composite-key counting sort (batch in low grid bits = XCD-pinned) ----
  hipMemsetAsync(counts, 0, (size_t)NB * NK * sizeof(int), stream);
  k_hist<<<dim3(((NED + 255) / 256) * 8), 256, 0, stream>>>(ei, counts);
  k_scan<<<NB, 1024, 0, stream>>>(counts, rows, cursor);
  k_scatter<<<dim3(((NED + 255) / 256) * 8), 256, 0, stream>>>(ei, cursor, dst_s);

  const int nwg = (NND + 63) / 64;   // 157
  for (int bb = 0; bb < NB; bb += Z) {
    k_gemm1<<<dim3(nwg << zsh), 512, 0, stream>>>(
        x, wchi, wclo, h1, a_heads, as1, ad1, bb, zsh);
    k_agg1<<<dim3(2500 << zsh), 256, 0, stream>>>(rows, dst_s, h1, as1, ad1,
                                                  xchi, xclo, bb, zsh);
    k_gemm2<<<dim3(nwg << zsh), 256, 0, stream>>>(
        xchi, xclo, wohi, wolo, h2, a_out, as2, ad2, bb, zsh);
    k_agg2<<<dim3(2500 << zsh), 256, 0, stream>>>(rows, dst_s, h2, as2, ad2,
                                                  out, bb, zsh);
  }
  (void)in_sizes; (void)n_in; (void)out_size;
}

// Round 16
// 448.019 us; speedup vs baseline: 1.4350x; 1.4350x over previous
//
#include <hip/hip_runtime.h>
#include <cstdint>
#include <cstddef>

// Problem shape (fixed by setup_inputs)
#define NND   10000     // nodes per graph
#define NED   160000    // edges per graph
#define NB    8         // batch
#define NF    256       // in features
#define NHID  64        // hidden per head
#define HEADS 8
#define F1    512       // HEADS*NHID
#define NCLS  64        // out classes

#define QSH   10        // dst-block shift (1024 nodes = 1MB h1 window)
#define NQ    10        // ceil(NND / 1024)
#define NK    (NND * NQ)  // composite key space per batch
#define CHNK  1024      // keys per scan chunk
#define NCH   ((NK + CHNK - 1) / CHNK)   // 98

#define ALPHA_SLOPE 0.2f
#define OUT_SLOPE   0.01f
#define EPS         1e-16f

typedef unsigned short u16;
typedef short short8 __attribute__((ext_vector_type(8)));
typedef float f32x4 __attribute__((ext_vector_type(4)));

// ---------------- ws layout (byte offsets, 16B-aligned) ----------------
static const size_t B_WCHI = 0;                      // u16 frag-order gemm1 B
static const size_t B_WCLO = 262144;
static const size_t B_WOHI = 524288;                 // u16 frag-order gemm2 B
static const size_t B_WOLO = 589824;
static const size_t B_AS1  = 655360;                 // f32 [8][N][8]
static const size_t B_AD1  = 3215360;
static const size_t B_AS2  = 5775360;                // f32 [8][N]
static const size_t B_AD2  = 6095360;
static const size_t B_CNT  = 6415360;                // int [8][NK]  (3.2MB)
static const size_t B_CUR  = 9615360;                // int [8][NK]  (3.2MB)
static const size_t B_ROWS = 12815360;               // int [8][N+1]
static const size_t B_BSUM = 13135424;               // int [8][NCH] (pad 16KB)
static const size_t B_DST  = 13151808;               // u16 [8][E]
static const size_t B_SCR  = 15711808;               // Z slots
// per-z slot layout in u16 units (ZSTRU total):
//   off 0:          xchi [N][F1]
//   off 5,120,000:  xclo [N][F1]
//   off 10,240,000: h1   [N][F1]   (node-major)
//   off 15,360,000: h2   [N][NCLS]
#define ZSTRU 16000000ull
static const size_t S_PERZ = 2 * ZSTRU;              // bytes = 32,000,000

// ---------------- helpers ----------------
__device__ __forceinline__ u16 f32_to_bf16_rn(float f) {
  uint32_t u = __float_as_uint(f);
  uint32_t r = u + 0x7fffu + ((u >> 16) & 1u);
  return (u16)(r >> 16);
}
__device__ __forceinline__ float bf16_to_f32(u16 s) {
  return __uint_as_float((uint32_t)s << 16);
}
__device__ __forceinline__ void split1(float v, u16& h, u16& l) {
  h = f32_to_bf16_rn(v);
  float r = v - bf16_to_f32(h);
  l = f32_to_bf16_rn(r);
}

// ---------------- weight prep ----------------
__global__ __launch_bounds__(256) void k_wsplit1(const float* __restrict__ Whd,
                                                 u16* __restrict__ hi,
                                                 u16* __restrict__ lo) {
  int t = blockIdx.x * 256 + threadIdx.x;   // 16384 threads
  int lane = t & 63;
  int frag = t >> 6;                        // 0..255
  int nj = frag & 3;
  int wq = (frag >> 2) & 3;
  int ts = (frag >> 4) & 7;
  int by = frag >> 7;
  int lm = lane & 15, lkg = lane >> 4;
  int n = by * 256 + wq * 64 + nj * 16 + lm;
  int h = n >> 6, nc = n & 63;
  u16 hv[8], lv[8];
#pragma unroll
  for (int j = 0; j < 8; ++j) {
    int k = ts * 32 + lkg * 8 + j;
    split1(Whd[h * (NF * NHID) + k * NHID + nc], hv[j], lv[j]);
  }
  size_t o = (size_t)t * 8;
  *(ushort4*)(hi + o) = make_ushort4(hv[0], hv[1], hv[2], hv[3]);
  *(ushort4*)(hi + o + 4) = make_ushort4(hv[4], hv[5], hv[6], hv[7]);
  *(ushort4*)(lo + o) = make_ushort4(lv[0], lv[1], lv[2], lv[3]);
  *(ushort4*)(lo + o + 4) = make_ushort4(lv[4], lv[5], lv[6], lv[7]);
}

__global__ __launch_bounds__(256) void k_wsplit2(const float* __restrict__ Wo,
                                                 u16* __restrict__ hi,
                                                 u16* __restrict__ lo) {
  int t = blockIdx.x * 256 + threadIdx.x;   // 4096 threads
  int lane = t & 63;
  int frag = t >> 6;                        // 0..63
  int nj = frag & 3, ts = frag >> 2;
  int lm = lane & 15, lkg = lane >> 4;
  int n = nj * 16 + lm;
  u16 hv[8], lv[8];
#pragma unroll
  for (int j = 0; j < 8; ++j) {
    int k = ts * 32 + lkg * 8 + j;
    split1(Wo[k * NCLS + n], hv[j], lv[j]);
  }
  size_t o = (size_t)t * 8;
  *(ushort4*)(hi + o) = make_ushort4(hv[0], hv[1], hv[2], hv[3]);
  *(ushort4*)(hi + o + 4) = make_ushort4(hv[4], hv[5], hv[6], hv[7]);
  *(ushort4*)(lo + o) = make_ushort4(lv[0], lv[1], lv[2], lv[3]);
  *(ushort4*)(lo + o + 4) = make_ushort4(lv[4], lv[5], lv[6], lv[7]);
}

// ---------------- layer-1 GEMM: BM=64, BN=512; 512 thr, 8 waves = 8 heads ---
__global__ __launch_bounds__(512) void k_gemm1(
    const float* __restrict__ x,
    const u16* __restrict__ Bfh, const u16* __restrict__ Bfl,
    u16* __restrict__ h1_s,
    const float* __restrict__ avec,
    float* __restrict__ as_g, float* __restrict__ ad_g,
    int base_b, int zsh) {
  __shared__ u16 As_hi[64][40];
  __shared__ u16 As_lo[64][40];

  const int zmask = (1 << zsh) - 1;
  const int z = blockIdx.x & zmask;
  const int wg = blockIdx.x >> zsh;        // 0..156
  const int b = base_b + z;
  const float* A = x + (size_t)b * NND * NF;
  u16* C = h1_s + (size_t)z * ZSTRU;
  float* as_ = as_g + (size_t)b * NND * 8;
  float* ad_ = ad_g + (size_t)b * NND * 8;

  const int m0 = wg * 64;
  const int tid = threadIdx.x;
  const int lane = tid & 63;
  const int w = tid >> 6;            // 0..7 == head
  const int lm = lane & 15;
  const int lkg = lane >> 4;
  const int by = w >> 2, wq = w & 3;

  f32x4 acc[4][4];
#pragma unroll
  for (int mi = 0; mi < 4; ++mi)
#pragma unroll
    for (int nj = 0; nj < 4; ++nj) acc[mi][nj] = 0.f;

  for (int t = 0; t < 8; ++t) {
    const int kk = t * 32;
    __syncthreads();
    {
      int rr = tid >> 3, kf = (tid & 7) * 4;
      int gm = m0 + rr;
      float4 v = make_float4(0.f, 0.f, 0.f, 0.f);
      if (gm < NND) v = *(const float4*)(A + (size_t)gm * NF + kk + kf);
      ushort4 hv, lv;
      split1(v.x, hv.x, lv.x); split1(v.y, hv.y, lv.y);
      split1(v.z, hv.z, lv.z); split1(v.w, hv.w, lv.w);
      *(ushort4*)&As_hi[rr][kf] = hv;
      *(ushort4*)&As_lo[rr][kf] = lv;
    }
    short8 bh[4], bl[4];
    {
      size_t fb = (((size_t)(by * 8 + t) * 4 + wq) * 4) * 512 + (size_t)lane * 8;
#pragma unroll
      for (int nj = 0; nj < 4; ++nj) {
        bh[nj] = *(const short8*)(Bfh + fb + nj * 512);
        bl[nj] = *(const short8*)(Bfl + fb + nj * 512);
      }
    }
    __syncthreads();

    short8 ah[4], al[4];
#pragma unroll
    for (int mi = 0; mi < 4; ++mi) {
      int row = mi * 16 + lm;
      ah[mi] = *(const short8*)&As_hi[row][lkg * 8];
      al[mi] = *(const short8*)&As_lo[row][lkg * 8];
    }
#pragma unroll
    for (int mi = 0; mi < 4; ++mi)
#pragma unroll
      for (int nj = 0; nj < 4; ++nj) {
        acc[mi][nj] = __builtin_amdgcn_mfma_f32_16x16x32_bf16(ah[mi], bh[nj], acc[mi][nj], 0, 0, 0);
        acc[mi][nj] = __builtin_amdgcn_mfma_f32_16x16x32_bf16(ah[mi], bl[nj], acc[mi][nj], 0, 0, 0);
        acc[mi][nj] = __builtin_amdgcn_mfma_f32_16x16x32_bf16(al[mi], bh[nj], acc[mi][nj], 0, 0, 0);
      }
  }

  const int hb = w;
  const int n0 = w * 64;
  float a_sv[4], a_dv[4];
#pragma unroll
  for (int nj = 0; nj < 4; ++nj) {
    a_sv[nj] = avec[hb * 128 + nj * 16 + lm];
    a_dv[nj] = avec[hb * 128 + 64 + nj * 16 + lm];
  }
#pragma unroll
  for (int mi = 0; mi < 4; ++mi) {
#pragma unroll
    for (int rr = 0; rr < 4; ++rr) {
      int gm = m0 + mi * 16 + lkg * 4 + rr;
      float ps = acc[mi][0][rr] * a_sv[0] + acc[mi][1][rr] * a_sv[1] +
                 acc[mi][2][rr] * a_sv[2] + acc[mi][3][rr] * a_sv[3];
      float pd = acc[mi][0][rr] * a_dv[0] + acc[mi][1][rr] * a_dv[1] +
                 acc[mi][2][rr] * a_dv[2] + acc[mi][3][rr] * a_dv[3];
#pragma unroll
      for (int off = 1; off < 16; off <<= 1) {
        ps += __shfl_xor(ps, off, 16);
        pd += __shfl_xor(pd, off, 16);
      }
      if (gm < NND) {
#pragma unroll
        for (int nj = 0; nj < 4; ++nj)
          C[(size_t)gm * F1 + n0 + nj * 16 + lm] = f32_to_bf16_rn(acc[mi][nj][rr]);
        if (lm == 0) {
          as_[(size_t)gm * 8 + hb] = ps;
          ad_[(size_t)gm * 8 + hb] = pd;
        }
      }
    }
  }
}

// ---------------- layer-2 GEMM: BM=64 (4 waves x 16 rows), BN=64 ------------
__global__ __launch_bounds__(256) void k_gemm2(
    const u16* __restrict__ Ahi_s, const u16* __restrict__ Alo_s,
    const u16* __restrict__ Bfh, const u16* __restrict__ Bfl,
    u16* __restrict__ C_s,
    const float* __restrict__ avec,
    float* __restrict__ as_g, float* __restrict__ ad_g,
    int base_b, int zsh) {
  __shared__ u16 As_hi[64][40];
  __shared__ u16 As_lo[64][40];

  const int zmask = (1 << zsh) - 1;
  const int z = blockIdx.x & zmask;
  const int wg = blockIdx.x >> zsh;        // 0..156
  const int b = base_b + z;
  const u16* Ahi = Ahi_s + (size_t)z * ZSTRU;
  const u16* Alo = Alo_s + (size_t)z * ZSTRU;
  u16* C = C_s + (size_t)z * ZSTRU;
  float* as_ = as_g + (size_t)b * NND;
  float* ad_ = ad_g + (size_t)b * NND;

  const int tid = threadIdx.x;
  const int lane = tid & 63;
  const int w = tid >> 6;
  const int lm = lane & 15;
  const int lkg = lane >> 4;
  const int m0 = wg * 64;

  f32x4 acc[4];
#pragma unroll
  for (int j = 0; j < 4; ++j) acc[j] = 0.f;

  for (int ts = 0; ts < 16; ++ts) {
    const int kk = ts * 32;
    __syncthreads();
#pragma unroll
    for (int u = 0; u < 2; ++u) {
      int e = u * 256 + tid;
      int rr = e >> 3, kf = (e & 7) * 4;
      int gm = m0 + rr;
      ushort4 hv = make_ushort4(0, 0, 0, 0), lv = make_ushort4(0, 0, 0, 0);
      if (gm < NND) {
        size_t g = (size_t)gm * F1 + kk + kf;
        hv = *(const ushort4*)(Ahi + g);
        lv = *(const ushort4*)(Alo + g);
      }
      *(ushort4*)&As_hi[rr][kf] = hv;
      *(ushort4*)&As_lo[rr][kf] = lv;
    }
    short8 bh[4], bl[4];
    {
      size_t fb = (size_t)(ts * 4) * 512 + (size_t)lane * 8;
#pragma unroll
      for (int nj = 0; nj < 4; ++nj) {
        bh[nj] = *(const short8*)(Bfh + fb + nj * 512);
        bl[nj] = *(const short8*)(Bfl + fb + nj * 512);
      }
    }
    __syncthreads();

    short8 ah, al;
    {
      int row = w * 16 + lm;
      ah = *(const short8*)&As_hi[row][lkg * 8];
      al = *(const short8*)&As_lo[row][lkg * 8];
    }
#pragma unroll
    for (int nj = 0; nj < 4; ++nj) {
      acc[nj] = __builtin_amdgcn_mfma_f32_16x16x32_bf16(ah, bh[nj], acc[nj], 0, 0, 0);
      acc[nj] = __builtin_amdgcn_mfma_f32_16x16x32_bf16(ah, bl[nj], acc[nj], 0, 0, 0);
      acc[nj] = __builtin_amdgcn_mfma_f32_16x16x32_bf16(al, bh[nj], acc[nj], 0, 0, 0);
    }
  }

  float a_sv[4], a_dv[4];
#pragma unroll
  for (int nj = 0; nj < 4; ++nj) {
    a_sv[nj] = avec[nj * 16 + lm];
    a_dv[nj] = avec[64 + nj * 16 + lm];
  }
#pragma unroll
  for (int rr = 0; rr < 4; ++rr) {
    int gm = m0 + w * 16 + lkg * 4 + rr;
    float ps = acc[0][rr] * a_sv[0] + acc[1][rr] * a_sv[1] +
               acc[2][rr] * a_sv[2] + acc[3][rr] * a_sv[3];
    float pd = acc[0][rr] * a_dv[0] + acc[1][rr] * a_dv[1] +
               acc[2][rr] * a_dv[2] + acc[3][rr] * a_dv[3];
#pragma unroll
    for (int off = 1; off < 16; off <<= 1) {
      ps += __shfl_xor(ps, off, 16);
      pd += __shfl_xor(pd, off, 16);
    }
    if (gm < NND) {
#pragma unroll
      for (int nj = 0; nj < 4; ++nj)
        C[(size_t)gm * NCLS + nj * 16 + lm] = f32_to_bf16_rn(acc[nj][rr]);
      if (lm == 0) {
        as_[gm] = ps;
        ad_[gm] = pd;
      }
    }
  }
}

// ---- counting sort on composite key (src, dst>>QSH) — all XCD-pinned ----

__global__ __launch_bounds__(256) void k_hist(const int* __restrict__ ei,
                                              int* __restrict__ counts) {
  int z = blockIdx.x & 7;
  int blk = blockIdx.x >> 3;
  int e = blk * 256 + threadIdx.x;
  if (e < NED) {
    int s = ei[(size_t)z * 2 * NED + e];
    int d = ei[(size_t)z * 2 * NED + NED + e];
    atomicAdd(&counts[(size_t)z * NK + s * NQ + (d >> QSH)], 1);
  }
}

// hierarchical scan over NK keys per batch: psum -> bscan -> apply
__global__ __launch_bounds__(256) void k_psum(const int* __restrict__ counts,
                                              int* __restrict__ bsum) {
  __shared__ int lds[256];
  int b = blockIdx.x & 7;
  int c = blockIdx.x >> 3;
  const int* cb = counts + (size_t)b * NK + c * CHNK;
  int rem = NK - c * CHNK;
  int i4 = threadIdx.x * 4;
  int s = 0;
  if (i4 + 3 < rem) {
    int4 v = *(const int4*)(cb + i4);
    s = v.x + v.y + v.z + v.w;
  } else {
    for (int j = 0; j < 4; ++j) if (i4 + j < rem) s += cb[i4 + j];
  }
  lds[threadIdx.x] = s;
  __syncthreads();
  for (int off = 128; off; off >>= 1) {
    if (threadIdx.x < off) lds[threadIdx.x] += lds[threadIdx.x + off];
    __syncthreads();
  }
  if (threadIdx.x == 0) bsum[b * NCH + c] = lds[0];
}

__global__ __launch_bounds__(1024) void k_bscan(int* __restrict__ bsum) {
  __shared__ int lds[8][128];
  int b = threadIdx.x >> 7;
  int j = threadIdx.x & 127;
  int v = (j < NCH) ? bsum[b * NCH + j] : 0;
  lds[b][j] = v;
  __syncthreads();
  for (int off = 1; off < 128; off <<= 1) {
    int t = (j >= off) ? lds[b][j - off] : 0;
    __syncthreads();
    lds[b][j] += t;
    __syncthreads();
  }
  if (j < NCH) bsum[b * NCH + j] = lds[b][j] - v;   // exclusive
}

__global__ __launch_bounds__(256) void k_apply(const int* __restrict__ counts,
                                               const int* __restrict__ bsum,
                                               int* __restrict__ cursor,
                                               int* __restrict__ rows) {
  __shared__ int lds[256];
  int b = blockIdx.x & 7;
  int c = blockIdx.x >> 3;
  const int* cb = counts + (size_t)b * NK + c * CHNK;
  int* cu = cursor + (size_t)b * NK + c * CHNK;
  int* rb = rows + b * (NND + 1);
  int rem = NK - c * CHNK;
  int i4 = threadIdx.x * 4;
  int v[4];
  int s = 0;
#pragma unroll
  for (int j = 0; j < 4; ++j) {
    v[j] = (i4 + j < rem) ? cb[i4 + j] : 0;
    s += v[j];
  }
  lds[threadIdx.x] = s;
  __syncthreads();
  for (int off = 1; off < 256; off <<= 1) {
    int t = (threadIdx.x >= off) ? lds[threadIdx.x - off] : 0;
    __syncthreads();
    lds[threadIdx.x] += t;
    __syncthreads();
  }
  int run = bsum[b * NCH + c] + lds[threadIdx.x] - s;
#pragma unroll
  for (int j = 0; j < 4; ++j) {
    int i = i4 + j;
    if (i < rem) {
      cu[i] = run;
      int gk = c * CHNK + i;
      if (gk % NQ == 0) {
        int n = gk / NQ;
        if (n < NND) rb[n] = run;
      }
      run += v[j];
    }
  }
  if (c == 0 && threadIdx.x == 0) rb[NND] = NED;
}

__global__ __launch_bounds__(256) void k_scatter(const int* __restrict__ ei,
                                                 int* __restrict__ cursor,
                                                 u16* __restrict__ dst_s) {
  int z = blockIdx.x & 7;
  int blk = blockIdx.x >> 3;
  int e = blk * 256 + threadIdx.x;
  if (e < NED) {
    int s = ei[(size_t)z * 2 * NED + e];
    int d = ei[(size_t)z * 2 * NED + NED + e];
    int pos = atomicAdd(&cursor[(size_t)z * NK + s * NQ + (d >> QSH)], 1);
    dst_s[(size_t)z * NED + pos] = (u16)d;
  }
}

#define UPK8(q, e) do { \
  acc[0] = fmaf(e, __uint_as_float((q).x << 16), acc[0]); \
  acc[1] = fmaf(e, __uint_as_float((q).x & 0xffff0000u), acc[1]); \
  acc[2] = fmaf(e, __uint_as_float((q).y << 16), acc[2]); \
  acc[3] = fmaf(e, __uint_as_float((q).y & 0xffff0000u), acc[3]); \
  acc[4] = fmaf(e, __uint_as_float((q).z << 16), acc[4]); \
  acc[5] = fmaf(e, __uint_as_float((q).z & 0xffff0000u), acc[5]); \
  acc[6] = fmaf(e, __uint_as_float((q).w << 16), acc[6]); \
  acc[7] = fmaf(e, __uint_as_float((q).w & 0xffff0000u), acc[7]); \
} while (0)

#define LKY(t) ((t) >= 0.f ? (t) : ALPHA_SLOPE * (t))

// layer-1 CSR agg, fused score + elu, writes split-bf16 xc. one wave/node.
__global__ __launch_bounds__(256) void k_agg1(
    const int* __restrict__ rows_g, const u16* __restrict__ dst_g,
    const u16* __restrict__ h1_s,
    const float* __restrict__ as_g, const float* __restrict__ ad_g,
    u16* __restrict__ xchi_s, u16* __restrict__ xclo_s,
    int base_b, int zsh) {
  const int zmask = (1 << zsh) - 1;
  const int z = blockIdx.x & zmask;
  const int idx = blockIdx.x >> zsh;       // 0..2499
  const int b = base_b + z;
  const int* rows = rows_g + (size_t)b * (NND + 1);
  const u16* dst = dst_g + (size_t)b * NED;
  const u16* h1 = h1_s + (size_t)z * ZSTRU;
  const float* as_ = as_g + (size_t)b * NND * 8;
  const float* ad_ = ad_g + (size_t)b * NND * 8;
  u16* xh = xchi_s + (size_t)z * ZSTRU;
  u16* xl = xclo_s + (size_t)z * ZSTRU;

  int lane = threadIdx.x & 63;
  int n = (idx * 256 + threadIdx.x) >> 6;
  if (n >= NND) return;
  const int hh = lane >> 3;
  const float asv = as_[n * 8 + hh];
  int beg = rows[n], end = rows[n + 1];
  float acc[8] = {};
  float den = 0.f;
  int i = beg;
  for (; i + 4 <= end; i += 4) {
    int d0 = dst[i], d1 = dst[i + 1], d2 = dst[i + 2], d3 = dst[i + 3];
    float t0 = LKY(asv + ad_[d0 * 8 + hh]);
    float t1 = LKY(asv + ad_[d1 * 8 + hh]);
    float t2 = LKY(asv + ad_[d2 * 8 + hh]);
    float t3 = LKY(asv + ad_[d3 * 8 + hh]);
    float e0 = __expf(-t0), e1 = __expf(-t1);
    float e2 = __expf(-t2), e3 = __expf(-t3);
    uint4 q0 = *((const uint4*)(h1 + (size_t)d0 * F1) + lane);
    uint4 q1 = *((const uint4*)(h1 + (size_t)d1 * F1) + lane);
    uint4 q2 = *((const uint4*)(h1 + (size_t)d2 * F1) + lane);
    uint4 q3 = *((const uint4*)(h1 + (size_t)d3 * F1) + lane);
    UPK8(q0, e0); UPK8(q1, e1); UPK8(q2, e2); UPK8(q3, e3);
    den += (e0 + e1) + (e2 + e3);
  }
  for (; i < end; ++i) {
    int d0 = dst[i];
    float t0 = LKY(asv + ad_[d0 * 8 + hh]);
    float e0 = __expf(-t0);
    uint4 q0 = *((const uint4*)(h1 + (size_t)d0 * F1) + lane);
    UPK8(q0, e0);
    den += e0;
  }
  float inv = 1.f / (den + EPS);
  u16 oh[8], ol[8];
#pragma unroll
  for (int j = 0; j < 8; ++j) {
    float v = acc[j] * inv;
    v = v > 0.f ? v : expm1f(v);
    split1(v, oh[j], ol[j]);
  }
  size_t wo = (size_t)n * F1 + lane * 8;
  *(ushort4*)(xh + wo) = make_ushort4(oh[0], oh[1], oh[2], oh[3]);
  *(ushort4*)(xh + wo + 4) = make_ushort4(oh[4], oh[5], oh[6], oh[7]);
  *(ushort4*)(xl + wo) = make_ushort4(ol[0], ol[1], ol[2], ol[3]);
  *(ushort4*)(xl + wo + 4) = make_ushort4(ol[4], ol[5], ol[6], ol[7]);
}

// layer-2 CSR agg, fused score + leaky output. one wave/node, lane=feature.
__global__ __launch_bounds__(256) void k_agg2(
    const int* __restrict__ rows_g, const u16* __restrict__ dst_g,
    const u16* __restrict__ h2_s,
    const float* __restrict__ as_g, const float* __restrict__ ad_g,
    float* __restrict__ out, int base_b, int zsh) {
  const int zmask = (1 << zsh) - 1;
  const int z = blockIdx.x & zmask;
  const int idx = blockIdx.x >> zsh;
  const int b = base_b + z;
  const int* rows = rows_g + (size_t)b * (NND + 1);
  const u16* dst = dst_g + (size_t)b * NED;
  const u16* h2 = h2_s + (size_t)z * ZSTRU;
  const float* as_ = as_g + (size_t)b * NND;
  const float* ad_ = ad_g + (size_t)b * NND;
  float* ob = out + (size_t)b * NND * NCLS;

  int lane = threadIdx.x & 63;
  int n = (idx * 256 + threadIdx.x) >> 6;
  if (n >= NND) return;
  const float asv = as_[n];
  int beg = rows[n], end = rows[n + 1];
  float acc = 0.f, den = 0.f;
  int i = beg;
  for (; i + 4 <= end; i += 4) {
    int d0 = dst[i], d1 = dst[i + 1], d2 = dst[i + 2], d3 = dst[i + 3];
    float t0 = LKY(asv + ad_[d0]);
    float t1 = LKY(asv + ad_[d1]);
    float t2 = LKY(asv + ad_[d2]);
    float t3 = LKY(asv + ad_[d3]);
    float e0 = __expf(-t0), e1 = __expf(-t1);
    float e2 = __expf(-t2), e3 = __expf(-t3);
    float h0 = bf16_to_f32(h2[(size_t)d0 * NCLS + lane]);
    float h1v = bf16_to_f32(h2[(size_t)d1 * NCLS + lane]);
    float h2v = bf16_to_f32(h2[(size_t)d2 * NCLS + lane]);
    float h3v = bf16_to_f32(h2[(size_t)d3 * NCLS + lane]);
    acc = fmaf(e0, h0, acc); acc = fmaf(e1, h1v, acc);
    acc = fmaf(e2, h2v, acc); acc = fmaf(e3, h3v, acc);
    den += (e0 + e1) + (e2 + e3);
  }
  for (; i < end; ++i) {
    int d0 = dst[i];
    float t0 = LKY(asv + ad_[d0]);
    float e0 = __expf(-t0);
    acc = fmaf(e0, bf16_to_f32(h2[(size_t)d0 * NCLS + lane]), acc);
    den += e0;
  }
  float v = acc / (den + EPS);
  ob[(size_t)n * NCLS + lane] = v >= 0.f ? v : OUT_SLOPE * v;
}

// ---------------- launcher ----------------
extern "C" void kernel_launch(void* const* d_in, const int* in_sizes, int n_in,
                              void* d_out, int out_size, void* d_ws, size_t ws_size,
                              hipStream_t stream) {
  const float* x       = (const float*)d_in[0];   // [B,N,256]
  const int*   ei      = (const int*)d_in[1];     // [B,2,E]
  const float* W_heads = (const float*)d_in[2];   // [8,256,64]
  const float* a_heads = (const float*)d_in[3];   // [8,128]
  const float* W_out   = (const float*)d_in[4];   // [512,64]
  const float* a_out   = (const float*)d_in[5];   // [128]
  float* out = (float*)d_out;

  char* base = (char*)d_ws;
  u16* wchi = (u16*)(base + B_WCHI);
  u16* wclo = (u16*)(base + B_WCLO);
  u16* wohi = (u16*)(base + B_WOHI);
  u16* wolo = (u16*)(base + B_WOLO);
  float* as1 = (float*)(base + B_AS1);
  float* ad1 = (float*)(base + B_AD1);
  float* as2 = (float*)(base + B_AS2);
  float* ad2 = (float*)(base + B_AD2);
  int* counts    = (int*)(base + B_CNT);
  int* cursor    = (int*)(base + B_CUR);
  int* rows      = (int*)(base + B_ROWS);
  int* bsum      = (int*)(base + B_BSUM);
  u16* dst_s     = (u16*)(base + B_DST);
  u16* scr       = (u16*)(base + B_SCR);

  int Z = 1, zsh = 0;
  if (ws_size >= B_SCR + 8 * S_PERZ) { Z = 8; zsh = 3; }
  else if (ws_size >= B_SCR + 4 * S_PERZ) { Z = 4; zsh = 2; }
  else if (ws_size >= B_SCR + 2 * S_PERZ) { Z = 2; zsh = 1; }

  u16* xchi = scr + 0;
  u16* xclo = scr + 5120000;
  u16* h1   = scr + 10240000;
  u16* h2   = scr + 15360000;

  // weight prep (once per call)
  k_wsplit1<<<64, 256, 0, stream>>>(W_heads, wchi, wclo);
  k_wsplit2<<<16, 256, 0, stream>>>(W_out, wohi, wolo);

  // ---- composite-key counting sort (batch in low grid bits = XCD-pinned) ----
  hipMemsetAsync(counts, 0, (size_t)NB * NK * sizeof(int), stream);
  k_hist<<<dim3(((NED + 255) / 256) * 8), 256, 0, stream>>>(ei, counts);
  k_psum<<<dim3(NCH * 8), 256, 0, stream>>>(counts, bsum);
  k_bscan<<<1, 1024, 0, stream>>>(bsum);
  k_apply<<<dim3(NCH * 8), 256, 0, stream>>>(counts, bsum, cursor, rows);
  k_scatter<<<dim3(((NED + 255) / 256) * 8), 256, 0, stream>>>(ei, cursor, dst_s);

  const int nwg = (NND + 63) / 64;   // 157
  for (int bb = 0; bb < NB; bb += Z) {
    k_gemm1<<<dim3(nwg << zsh), 512, 0, stream>>>(
        x, wchi, wclo, h1, a_heads, as1, ad1, bb, zsh);
    k_agg1<<<dim3(2500 << zsh), 256, 0, stream>>>(rows, dst_s, h1, as1, ad1,
                                                  xchi, xclo, bb, zsh);
    k_gemm2<<<dim3(nwg << zsh), 256, 0, stream>>>(
        xchi, xclo, wohi, wolo, h2, a_out, as2, ad2, bb, zsh);
    k_agg2<<<dim3(2500 << zsh), 256, 0, stream>>>(rows, dst_s, h2, as2, ad2,
                                                  out, bb, zsh);
  }
  (void)in_sizes; (void)n_in; (void)out_size;
}

// Round 17
// 419.220 us; speedup vs baseline: 1.5336x; 1.0687x over previous
//
#include <hip/hip_runtime.h>
#include <cstdint>
#include <cstddef>

// Problem shape (fixed by setup_inputs)
#define NND   10000     // nodes per graph
#define NED   160000    // edges per graph
#define NB    8         // batch
#define NF    256       // in features
#define NHID  64        // hidden per head
#define HEADS 8
#define F1    512       // HEADS*NHID
#define NCLS  64        // out classes

#define CHNK  1024      // keys per scan chunk
#define NCH   10        // ceil(NND/CHNK)

#define ALPHA_SLOPE 0.2f
#define OUT_SLOPE   0.01f
#define EPS         1e-16f

typedef unsigned short u16;
typedef short short8 __attribute__((ext_vector_type(8)));
typedef float f32x4 __attribute__((ext_vector_type(4)));

// ---------------- ws layout (byte offsets, 16B-aligned) ----------------
static const size_t B_WCHI = 0;                      // u16 frag-order gemm1 B
static const size_t B_WCLO = 262144;
static const size_t B_WOHI = 524288;                 // u16 frag-order gemm2 B
static const size_t B_WOLO = 589824;
static const size_t B_AS1  = 655360;                 // f32 [8][N][8]
static const size_t B_AD1  = 3215360;
static const size_t B_AS2  = 5775360;                // f32 [8][N]
static const size_t B_AD2  = 6095360;
static const size_t B_CNT  = 6415360;                // int [8][N]
static const size_t B_CUR  = 6735360;                // int [8][N]
static const size_t B_ROWS = 7055360;                // int [8][N+1]
static const size_t B_BSUM = 7375392;                // int [8][16]
static const size_t B_DST  = 7375904;                // u16 [8][E]
static const size_t B_SCR  = 9935936;                // Z slots
// per-z slot layout in u16 units (ZSTRU total):
//   off 0:          xc [N][F1]    (single bf16)
//   off 5,120,000:  h1 [N][F1]    (node-major bf16)
//   off 10,240,000: h2 [N][NCLS]
#define ZSTRU 10880000ull
static const size_t S_PERZ = 2 * ZSTRU;              // bytes = 21,760,000

// ---------------- helpers ----------------
__device__ __forceinline__ u16 f32_to_bf16_rn(float f) {
  uint32_t u = __float_as_uint(f);
  uint32_t r = u + 0x7fffu + ((u >> 16) & 1u);
  return (u16)(r >> 16);
}
__device__ __forceinline__ float bf16_to_f32(u16 s) {
  return __uint_as_float((uint32_t)s << 16);
}
__device__ __forceinline__ void split1(float v, u16& h, u16& l) {
  h = f32_to_bf16_rn(v);
  float r = v - bf16_to_f32(h);
  l = f32_to_bf16_rn(r);
}

// ---------------- weight prep ----------------
__global__ __launch_bounds__(256) void k_wsplit1(const float* __restrict__ Whd,
                                                 u16* __restrict__ hi,
                                                 u16* __restrict__ lo) {
  int t = blockIdx.x * 256 + threadIdx.x;   // 16384 threads
  int lane = t & 63;
  int frag = t >> 6;                        // 0..255
  int nj = frag & 3;
  int wq = (frag >> 2) & 3;
  int ts = (frag >> 4) & 7;
  int by = frag >> 7;
  int lm = lane & 15, lkg = lane >> 4;
  int n = by * 256 + wq * 64 + nj * 16 + lm;
  int h = n >> 6, nc = n & 63;
  u16 hv[8], lv[8];
#pragma unroll
  for (int j = 0; j < 8; ++j) {
    int k = ts * 32 + lkg * 8 + j;
    split1(Whd[h * (NF * NHID) + k * NHID + nc], hv[j], lv[j]);
  }
  size_t o = (size_t)t * 8;
  *(ushort4*)(hi + o) = make_ushort4(hv[0], hv[1], hv[2], hv[3]);
  *(ushort4*)(hi + o + 4) = make_ushort4(hv[4], hv[5], hv[6], hv[7]);
  *(ushort4*)(lo + o) = make_ushort4(lv[0], lv[1], lv[2], lv[3]);
  *(ushort4*)(lo + o + 4) = make_ushort4(lv[4], lv[5], lv[6], lv[7]);
}

__global__ __launch_bounds__(256) void k_wsplit2(const float* __restrict__ Wo,
                                                 u16* __restrict__ hi,
                                                 u16* __restrict__ lo) {
  int t = blockIdx.x * 256 + threadIdx.x;   // 4096 threads
  int lane = t & 63;
  int frag = t >> 6;                        // 0..63
  int nj = frag & 3, ts = frag >> 2;
  int lm = lane & 15, lkg = lane >> 4;
  int n = nj * 16 + lm;
  u16 hv[8], lv[8];
#pragma unroll
  for (int j = 0; j < 8; ++j) {
    int k = ts * 32 + lkg * 8 + j;
    split1(Wo[k * NCLS + n], hv[j], lv[j]);
  }
  size_t o = (size_t)t * 8;
  *(ushort4*)(hi + o) = make_ushort4(hv[0], hv[1], hv[2], hv[3]);
  *(ushort4*)(hi + o + 4) = make_ushort4(hv[4], hv[5], hv[6], hv[7]);
  *(ushort4*)(lo + o) = make_ushort4(lv[0], lv[1], lv[2], lv[3]);
  *(ushort4*)(lo + o + 4) = make_ushort4(lv[4], lv[5], lv[6], lv[7]);
}

// ---------------- layer-1 GEMM: BM=64, BN=512; 512 thr, 8 waves = 8 heads ---
__global__ __launch_bounds__(512) void k_gemm1(
    const float* __restrict__ x,
    const u16* __restrict__ Bfh, const u16* __restrict__ Bfl,
    u16* __restrict__ h1_s,
    const float* __restrict__ avec,
    float* __restrict__ as_g, float* __restrict__ ad_g,
    int base_b, int zsh) {
  __shared__ u16 As_hi[64][40];
  __shared__ u16 As_lo[64][40];

  const int zmask = (1 << zsh) - 1;
  const int z = blockIdx.x & zmask;
  const int wg = blockIdx.x >> zsh;        // 0..156
  const int b = base_b + z;
  const float* A = x + (size_t)b * NND * NF;
  u16* C = h1_s + (size_t)z * ZSTRU;
  float* as_ = as_g + (size_t)b * NND * 8;
  float* ad_ = ad_g + (size_t)b * NND * 8;

  const int m0 = wg * 64;
  const int tid = threadIdx.x;
  const int lane = tid & 63;
  const int w = tid >> 6;            // 0..7 == head
  const int lm = lane & 15;
  const int lkg = lane >> 4;
  const int by = w >> 2, wq = w & 3;

  f32x4 acc[4][4];
#pragma unroll
  for (int mi = 0; mi < 4; ++mi)
#pragma unroll
    for (int nj = 0; nj < 4; ++nj) acc[mi][nj] = 0.f;

  for (int t = 0; t < 8; ++t) {
    const int kk = t * 32;
    __syncthreads();
    {
      int rr = tid >> 3, kf = (tid & 7) * 4;
      int gm = m0 + rr;
      float4 v = make_float4(0.f, 0.f, 0.f, 0.f);
      if (gm < NND) v = *(const float4*)(A + (size_t)gm * NF + kk + kf);
      ushort4 hv, lv;
      split1(v.x, hv.x, lv.x); split1(v.y, hv.y, lv.y);
      split1(v.z, hv.z, lv.z); split1(v.w, hv.w, lv.w);
      *(ushort4*)&As_hi[rr][kf] = hv;
      *(ushort4*)&As_lo[rr][kf] = lv;
    }
    short8 bh[4], bl[4];
    {
      size_t fb = (((size_t)(by * 8 + t) * 4 + wq) * 4) * 512 + (size_t)lane * 8;
#pragma unroll
      for (int nj = 0; nj < 4; ++nj) {
        bh[nj] = *(const short8*)(Bfh + fb + nj * 512);
        bl[nj] = *(const short8*)(Bfl + fb + nj * 512);
      }
    }
    __syncthreads();

    short8 ah[4], al[4];
#pragma unroll
    for (int mi = 0; mi < 4; ++mi) {
      int row = mi * 16 + lm;
      ah[mi] = *(const short8*)&As_hi[row][lkg * 8];
      al[mi] = *(const short8*)&As_lo[row][lkg * 8];
    }
#pragma unroll
    for (int mi = 0; mi < 4; ++mi)
#pragma unroll
      for (int nj = 0; nj < 4; ++nj) {
        acc[mi][nj] = __builtin_amdgcn_mfma_f32_16x16x32_bf16(ah[mi], bh[nj], acc[mi][nj], 0, 0, 0);
        acc[mi][nj] = __builtin_amdgcn_mfma_f32_16x16x32_bf16(ah[mi], bl[nj], acc[mi][nj], 0, 0, 0);
        acc[mi][nj] = __builtin_amdgcn_mfma_f32_16x16x32_bf16(al[mi], bh[nj], acc[mi][nj], 0, 0, 0);
      }
  }

  const int hb = w;
  const int n0 = w * 64;
  float a_sv[4], a_dv[4];
#pragma unroll
  for (int nj = 0; nj < 4; ++nj) {
    a_sv[nj] = avec[hb * 128 + nj * 16 + lm];
    a_dv[nj] = avec[hb * 128 + 64 + nj * 16 + lm];
  }
#pragma unroll
  for (int mi = 0; mi < 4; ++mi) {
#pragma unroll
    for (int rr = 0; rr < 4; ++rr) {
      int gm = m0 + mi * 16 + lkg * 4 + rr;
      float ps = acc[mi][0][rr] * a_sv[0] + acc[mi][1][rr] * a_sv[1] +
                 acc[mi][2][rr] * a_sv[2] + acc[mi][3][rr] * a_sv[3];
      float pd = acc[mi][0][rr] * a_dv[0] + acc[mi][1][rr] * a_dv[1] +
                 acc[mi][2][rr] * a_dv[2] + acc[mi][3][rr] * a_dv[3];
#pragma unroll
      for (int off = 1; off < 16; off <<= 1) {
        ps += __shfl_xor(ps, off, 16);
        pd += __shfl_xor(pd, off, 16);
      }
      if (gm < NND) {
#pragma unroll
        for (int nj = 0; nj < 4; ++nj)
          C[(size_t)gm * F1 + n0 + nj * 16 + lm] = f32_to_bf16_rn(acc[mi][nj][rr]);
        if (lm == 0) {
          as_[(size_t)gm * 8 + hb] = ps;
          ad_[(size_t)gm * 8 + hb] = pd;
        }
      }
    }
  }
}

// ---------------- layer-2 GEMM: BM=64 (4 waves x 16 rows), BN=64 ------------
// A = xc single bf16 (hi only); B frags (split) straight from L2.
__global__ __launch_bounds__(256) void k_gemm2(
    const u16* __restrict__ A_s,
    const u16* __restrict__ Bfh, const u16* __restrict__ Bfl,
    u16* __restrict__ C_s,
    const float* __restrict__ avec,
    float* __restrict__ as_g, float* __restrict__ ad_g,
    int base_b, int zsh) {
  __shared__ u16 As[64][40];

  const int zmask = (1 << zsh) - 1;
  const int z = blockIdx.x & zmask;
  const int wg = blockIdx.x >> zsh;        // 0..156
  const int b = base_b + z;
  const u16* Ah = A_s + (size_t)z * ZSTRU;
  u16* C = C_s + (size_t)z * ZSTRU;
  float* as_ = as_g + (size_t)b * NND;
  float* ad_ = ad_g + (size_t)b * NND;

  const int tid = threadIdx.x;
  const int lane = tid & 63;
  const int w = tid >> 6;
  const int lm = lane & 15;
  const int lkg = lane >> 4;
  const int m0 = wg * 64;

  f32x4 acc[4];
#pragma unroll
  for (int j = 0; j < 4; ++j) acc[j] = 0.f;

  for (int ts = 0; ts < 16; ++ts) {
    const int kk = ts * 32;
    __syncthreads();
    // stage A: 64 rows x 32 u16 = 512 ushort4 units
#pragma unroll
    for (int u = 0; u < 2; ++u) {
      int e = u * 256 + tid;
      int rr = e >> 3, kf = (e & 7) * 4;
      int gm = m0 + rr;
      ushort4 hv = make_ushort4(0, 0, 0, 0);
      if (gm < NND) hv = *(const ushort4*)(Ah + (size_t)gm * F1 + kk + kf);
      *(ushort4*)&As[rr][kf] = hv;
    }
    short8 bh[4], bl[4];
    {
      size_t fb = (size_t)(ts * 4) * 512 + (size_t)lane * 8;
#pragma unroll
      for (int nj = 0; nj < 4; ++nj) {
        bh[nj] = *(const short8*)(Bfh + fb + nj * 512);
        bl[nj] = *(const short8*)(Bfl + fb + nj * 512);
      }
    }
    __syncthreads();

    short8 ah;
    {
      int row = w * 16 + lm;
      ah = *(const short8*)&As[row][lkg * 8];
    }
#pragma unroll
    for (int nj = 0; nj < 4; ++nj) {
      acc[nj] = __builtin_amdgcn_mfma_f32_16x16x32_bf16(ah, bh[nj], acc[nj], 0, 0, 0);
      acc[nj] = __builtin_amdgcn_mfma_f32_16x16x32_bf16(ah, bl[nj], acc[nj], 0, 0, 0);
    }
  }

  float a_sv[4], a_dv[4];
#pragma unroll
  for (int nj = 0; nj < 4; ++nj) {
    a_sv[nj] = avec[nj * 16 + lm];
    a_dv[nj] = avec[64 + nj * 16 + lm];
  }
#pragma unroll
  for (int rr = 0; rr < 4; ++rr) {
    int gm = m0 + w * 16 + lkg * 4 + rr;
    float ps = acc[0][rr] * a_sv[0] + acc[1][rr] * a_sv[1] +
               acc[2][rr] * a_sv[2] + acc[3][rr] * a_sv[3];
    float pd = acc[0][rr] * a_dv[0] + acc[1][rr] * a_dv[1] +
               acc[2][rr] * a_dv[2] + acc[3][rr] * a_dv[3];
#pragma unroll
    for (int off = 1; off < 16; off <<= 1) {
      ps += __shfl_xor(ps, off, 16);
      pd += __shfl_xor(pd, off, 16);
    }
    if (gm < NND) {
#pragma unroll
      for (int nj = 0; nj < 4; ++nj)
        C[(size_t)gm * NCLS + nj * 16 + lm] = f32_to_bf16_rn(acc[nj][rr]);
      if (lm == 0) {
        as_[gm] = ps;
        ad_[gm] = pd;
      }
    }
  }
}

// ---- counting sort (simple src key) with hierarchical scan; XCD-pinned ----

__global__ __launch_bounds__(256) void k_hist(const int* __restrict__ ei,
                                              int* __restrict__ counts) {
  int z = blockIdx.x & 7;
  int blk = blockIdx.x >> 3;
  int e = blk * 256 + threadIdx.x;
  if (e < NED) {
    int s = ei[(size_t)z * 2 * NED + e];
    atomicAdd(&counts[z * NND + s], 1);
  }
}

__global__ __launch_bounds__(256) void k_psum(const int* __restrict__ counts,
                                              int* __restrict__ bsum) {
  __shared__ int lds[256];
  int b = blockIdx.x & 7;
  int c = blockIdx.x >> 3;                 // 0..NCH-1
  const int* cb = counts + (size_t)b * NND + c * CHNK;
  int rem = NND - c * CHNK;
  int i4 = threadIdx.x * 4;
  int s = 0;
  if (i4 + 3 < rem) {
    int4 v = *(const int4*)(cb + i4);
    s = v.x + v.y + v.z + v.w;
  } else {
    for (int j = 0; j < 4; ++j) if (i4 + j < rem) s += cb[i4 + j];
  }
  lds[threadIdx.x] = s;
  __syncthreads();
  for (int off = 128; off; off >>= 1) {
    if (threadIdx.x < off) lds[threadIdx.x] += lds[threadIdx.x + off];
    __syncthreads();
  }
  if (threadIdx.x == 0) bsum[b * 16 + c] = lds[0];
}

__global__ __launch_bounds__(128) void k_bscan(int* __restrict__ bsum) {
  __shared__ int lds[8][16];
  int b = threadIdx.x >> 4;
  int j = threadIdx.x & 15;
  int v = (j < NCH) ? bsum[b * 16 + j] : 0;
  lds[b][j] = v;
  __syncthreads();
  for (int off = 1; off < 16; off <<= 1) {
    int t = (j >= off) ? lds[b][j - off] : 0;
    __syncthreads();
    lds[b][j] += t;
    __syncthreads();
  }
  if (j < NCH) bsum[b * 16 + j] = lds[b][j] - v;   // exclusive
}

__global__ __launch_bounds__(256) void k_apply(const int* __restrict__ counts,
                                               const int* __restrict__ bsum,
                                               int* __restrict__ cursor,
                                               int* __restrict__ rows) {
  __shared__ int lds[256];
  int b = blockIdx.x & 7;
  int c = blockIdx.x >> 3;
  const int* cb = counts + (size_t)b * NND + c * CHNK;
  int* cu = cursor + (size_t)b * NND + c * CHNK;
  int* rb = rows + b * (NND + 1);
  int rem = NND - c * CHNK;
  int i4 = threadIdx.x * 4;
  int v[4];
  int s = 0;
#pragma unroll
  for (int j = 0; j < 4; ++j) {
    v[j] = (i4 + j < rem) ? cb[i4 + j] : 0;
    s += v[j];
  }
  lds[threadIdx.x] = s;
  __syncthreads();
  for (int off = 1; off < 256; off <<= 1) {
    int t = (threadIdx.x >= off) ? lds[threadIdx.x - off] : 0;
    __syncthreads();
    lds[threadIdx.x] += t;
    __syncthreads();
  }
  int run = bsum[b * 16 + c] + lds[threadIdx.x] - s;
#pragma unroll
  for (int j = 0; j < 4; ++j) {
    int i = i4 + j;
    if (i < rem) {
      cu[i] = run;
      rb[c * CHNK + i] = run;
      run += v[j];
    }
  }
  if (c == 0 && threadIdx.x == 0) rb[NND] = NED;
}

__global__ __launch_bounds__(256) void k_scatter(const int* __restrict__ ei,
                                                 int* __restrict__ cursor,
                                                 u16* __restrict__ dst_s) {
  int z = blockIdx.x & 7;
  int blk = blockIdx.x >> 3;
  int e = blk * 256 + threadIdx.x;
  if (e < NED) {
    int s = ei[(size_t)z * 2 * NED + e];
    int d = ei[(size_t)z * 2 * NED + NED + e];
    int pos = atomicAdd(&cursor[z * NND + s], 1);
    dst_s[(size_t)z * NED + pos] = (u16)d;
  }
}

#define UPK8(q, e) do { \
  acc[0] = fmaf(e, __uint_as_float((q).x << 16), acc[0]); \
  acc[1] = fmaf(e, __uint_as_float((q).x & 0xffff0000u), acc[1]); \
  acc[2] = fmaf(e, __uint_as_float((q).y << 16), acc[2]); \
  acc[3] = fmaf(e, __uint_as_float((q).y & 0xffff0000u), acc[3]); \
  acc[4] = fmaf(e, __uint_as_float((q).z << 16), acc[4]); \
  acc[5] = fmaf(e, __uint_as_float((q).z & 0xffff0000u), acc[5]); \
  acc[6] = fmaf(e, __uint_as_float((q).w << 16), acc[6]); \
  acc[7] = fmaf(e, __uint_as_float((q).w & 0xffff0000u), acc[7]); \
} while (0)

#define LKY(t) ((t) >= 0.f ? (t) : ALPHA_SLOPE * (t))

// layer-1 CSR agg, fused score + elu, writes single-bf16 xc. one wave/node.
__global__ __launch_bounds__(256) void k_agg1(
    const int* __restrict__ rows_g, const u16* __restrict__ dst_g,
    const u16* __restrict__ h1_s,
    const float* __restrict__ as_g, const float* __restrict__ ad_g,
    u16* __restrict__ xc_s,
    int base_b, int zsh) {
  const int zmask = (1 << zsh) - 1;
  const int z = blockIdx.x & zmask;
  const int idx = blockIdx.x >> zsh;       // 0..2499
  const int b = base_b + z;
  const int* rows = rows_g + (size_t)b * (NND + 1);
  const u16* dst = dst_g + (size_t)b * NED;
  const u16* h1 = h1_s + (size_t)z * ZSTRU;
  const float* as_ = as_g + (size_t)b * NND * 8;
  const float* ad_ = ad_g + (size_t)b * NND * 8;
  u16* xc = xc_s + (size_t)z * ZSTRU;

  int lane = threadIdx.x & 63;
  int n = (idx * 256 + threadIdx.x) >> 6;
  if (n >= NND) return;
  const int hh = lane >> 3;
  const float asv = as_[n * 8 + hh];
  int beg = rows[n], end = rows[n + 1];
  float acc[8] = {};
  float den = 0.f;
  int i = beg;
  for (; i + 4 <= end; i += 4) {
    int d0 = dst[i], d1 = dst[i + 1], d2 = dst[i + 2], d3 = dst[i + 3];
    float t0 = LKY(asv + ad_[d0 * 8 + hh]);
    float t1 = LKY(asv + ad_[d1 * 8 + hh]);
    float t2 = LKY(asv + ad_[d2 * 8 + hh]);
    float t3 = LKY(asv + ad_[d3 * 8 + hh]);
    float e0 = __expf(-t0), e1 = __expf(-t1);
    float e2 = __expf(-t2), e3 = __expf(-t3);
    uint4 q0 = *((const uint4*)(h1 + (size_t)d0 * F1) + lane);
    uint4 q1 = *((const uint4*)(h1 + (size_t)d1 * F1) + lane);
    uint4 q2 = *((const uint4*)(h1 + (size_t)d2 * F1) + lane);
    uint4 q3 = *((const uint4*)(h1 + (size_t)d3 * F1) + lane);
    UPK8(q0, e0); UPK8(q1, e1); UPK8(q2, e2); UPK8(q3, e3);
    den += (e0 + e1) + (e2 + e3);
  }
  for (; i < end; ++i) {
    int d0 = dst[i];
    float t0 = LKY(asv + ad_[d0 * 8 + hh]);
    float e0 = __expf(-t0);
    uint4 q0 = *((const uint4*)(h1 + (size_t)d0 * F1) + lane);
    UPK8(q0, e0);
    den += e0;
  }
  float inv = 1.f / (den + EPS);
  u16 oh[8];
#pragma unroll
  for (int j = 0; j < 8; ++j) {
    float v = acc[j] * inv;
    v = v > 0.f ? v : expm1f(v);
    oh[j] = f32_to_bf16_rn(v);
  }
  size_t wo = (size_t)n * F1 + lane * 8;
  *(ushort4*)(xc + wo) = make_ushort4(oh[0], oh[1], oh[2], oh[3]);
  *(ushort4*)(xc + wo + 4) = make_ushort4(oh[4], oh[5], oh[6], oh[7]);
}

// layer-2 CSR agg, fused score + leaky output. one wave/node, lane=feature.
__global__ __launch_bounds__(256) void k_agg2(
    const int* __restrict__ rows_g, const u16* __restrict__ dst_g,
    const u16* __restrict__ h2_s,
    const float* __restrict__ as_g, const float* __restrict__ ad_g,
    float* __restrict__ out, int base_b, int zsh) {
  const int zmask = (1 << zsh) - 1;
  const int z = blockIdx.x & zmask;
  const int idx = blockIdx.x >> zsh;
  const int b = base_b + z;
  const int* rows = rows_g + (size_t)b * (NND + 1);
  const u16* dst = dst_g + (size_t)b * NED;
  const u16* h2 = h2_s + (size_t)z * ZSTRU;
  const float* as_ = as_g + (size_t)b * NND;
  const float* ad_ = ad_g + (size_t)b * NND;
  float* ob = out + (size_t)b * NND * NCLS;

  int lane = threadIdx.x & 63;
  int n = (idx * 256 + threadIdx.x) >> 6;
  if (n >= NND) return;
  const float asv = as_[n];
  int beg = rows[n], end = rows[n + 1];
  float acc = 0.f, den = 0.f;
  int i = beg;
  for (; i + 4 <= end; i += 4) {
    int d0 = dst[i], d1 = dst[i + 1], d2 = dst[i + 2], d3 = dst[i + 3];
    float t0 = LKY(asv + ad_[d0]);
    float t1 = LKY(asv + ad_[d1]);
    float t2 = LKY(asv + ad_[d2]);
    float t3 = LKY(asv + ad_[d3]);
    float e0 = __expf(-t0), e1 = __expf(-t1);
    float e2 = __expf(-t2), e3 = __expf(-t3);
    float h0 = bf16_to_f32(h2[(size_t)d0 * NCLS + lane]);
    float h1v = bf16_to_f32(h2[(size_t)d1 * NCLS + lane]);
    float h2v = bf16_to_f32(h2[(size_t)d2 * NCLS + lane]);
    float h3v = bf16_to_f32(h2[(size_t)d3 * NCLS + lane]);
    acc = fmaf(e0, h0, acc); acc = fmaf(e1, h1v, acc);
    acc = fmaf(e2, h2v, acc); acc = fmaf(e3, h3v, acc);
    den += (e0 + e1) + (e2 + e3);
  }
  for (; i < end; ++i) {
    int d0 = dst[i];
    float t0 = LKY(asv + ad_[d0]);
    float e0 = __expf(-t0);
    acc = fmaf(e0, bf16_to_f32(h2[(size_t)d0 * NCLS + lane]), acc);
    den += e0;
  }
  float v = acc / (den + EPS);
  ob[(size_t)n * NCLS + lane] = v >= 0.f ? v : OUT_SLOPE * v;
}

// ---------------- launcher ----------------
extern "C" void kernel_launch(void* const* d_in, const int* in_sizes, int n_in,
                              void* d_out, int out_size, void* d_ws, size_t ws_size,
                              hipStream_t stream) {
  const float* x       = (const float*)d_in[0];   // [B,N,256]
  const int*   ei      = (const int*)d_in[1];     // [B,2,E]
  const float* W_heads = (const float*)d_in[2];   // [8,256,64]
  const float* a_heads = (const float*)d_in[3];   // [8,128]
  const float* W_out   = (const float*)d_in[4];   // [512,64]
  const float* a_out   = (const float*)d_in[5];   // [128]
  float* out = (float*)d_out;

  char* base = (char*)d_ws;
  u16* wchi = (u16*)(base + B_WCHI);
  u16* wclo = (u16*)(base + B_WCLO);
  u16* wohi = (u16*)(base + B_WOHI);
  u16* wolo = (u16*)(base + B_WOLO);
  float* as1 = (float*)(base + B_AS1);
  float* ad1 = (float*)(base + B_AD1);
  float* as2 = (float*)(base + B_AS2);
  float* ad2 = (float*)(base + B_AD2);
  int* counts    = (int*)(base + B_CNT);
  int* cursor    = (int*)(base + B_CUR);
  int* rows      = (int*)(base + B_ROWS);
  int* bsum      = (int*)(base + B_BSUM);
  u16* dst_s     = (u16*)(base + B_DST);
  u16* scr       = (u16*)(base + B_SCR);

  int Z = 1, zsh = 0;
  if (ws_size >= B_SCR + 8 * S_PERZ) { Z = 8; zsh = 3; }
  else if (ws_size >= B_SCR + 4 * S_PERZ) { Z = 4; zsh = 2; }
  else if (ws_size >= B_SCR + 2 * S_PERZ) { Z = 2; zsh = 1; }

  u16* xc = scr + 0;
  u16* h1 = scr + 5120000;
  u16* h2 = scr + 10240000;

  // weight prep (once per call)
  k_wsplit1<<<64, 256, 0, stream>>>(W_heads, wchi, wclo);
  k_wsplit2<<<16, 256, 0, stream>>>(W_out, wohi, wolo);

  // ---- counting sort (batch in low grid bits = XCD-pinned) ----
  hipMemsetAsync(counts, 0, (size_t)NB * NND * sizeof(int), stream);
  k_hist<<<dim3(((NED + 255) / 256) * 8), 256, 0, stream>>>(ei, counts);
  k_psum<<<dim3(NCH * 8), 256, 0, stream>>>(counts, bsum);
  k_bscan<<<1, 128, 0, stream>>>(bsum);
  k_apply<<<dim3(NCH * 8), 256, 0, stream>>>(counts, bsum, cursor, rows);
  k_scatter<<<dim3(((NED + 255) / 256) * 8), 256, 0, stream>>>(ei, cursor, dst_s);

  const int nwg = (NND + 63) / 64;   // 157
  for (int bb = 0; bb < NB; bb += Z) {
    k_gemm1<<<dim3(nwg << zsh), 512, 0, stream>>>(
        x, wchi, wclo, h1, a_heads, as1, ad1, bb, zsh);
    k_agg1<<<dim3(2500 << zsh), 256, 0, stream>>>(rows, dst_s, h1, as1, ad1,
                                                  xc, bb, zsh);
    k_gemm2<<<dim3(nwg << zsh), 256, 0, stream>>>(
        xc, wohi, wolo, h2, a_out, as2, ad2, bb, zsh);
    k_agg2<<<dim3(2500 << zsh), 256, 0, stream>>>(rows, dst_s, h2, as2, ad2,
                                                  out, bb, zsh);
  }
  (void)in_sizes; (void)n_in; (void)out_size;
}